// Round 3
// baseline (688.046 us; speedup 1.0000x reference)
//
#include <hip/hip_runtime.h>

// GNN TARnet: h = x*emb -> 2x graph conv -> two prob heads.
// R7: conv chain fused. k_aggregate+k_update+(next prepare) -> one k_conv
//     kernel: gather goes straight into LDS (agg array eliminated), update
//     FFN runs from LDS, and for conv1 the conv2-prepare FFN is fused as a
//     tail (rows already in LDS; W1p/W2p reuse the dead W1u LDS space).
//     13 dispatches -> 10; ~51 MB of agg/hB re-read traffic removed.
//     k_head kept byte-identical to R6 (proven at its ~3 TB/s pattern wall).

constexpr int B = 8, N = 5000, E = 160000, D = 64, H = 128;
constexpr int BN = B * N;           // 40000
constexpr int ND = N * D;           // 320000
constexpr long BND = (long)BN * D;  // 2,560,000
constexpr int KC = 320;             // k-chunk per head block
constexpr int NIT = KC / 8;         // 40 k-iters per thread
constexpr int XB = ND / KC;         // 1000 x-blocks per head

using f32x4 = __attribute__((ext_vector_type(4))) float;

__device__ __forceinline__ float elu_f(float x) {
    return x > 0.0f ? x : __expf(x) - 1.0f;
}

__device__ __forceinline__ void g2lds16(const float* g, float* l) {
    __builtin_amdgcn_global_load_lds(
        (const __attribute__((address_space(1))) void*)g,
        (__attribute__((address_space(3))) void*)l, 16, 0, 0);
}

// ---------------- CSR build (edges grouped by child) ----------------
__global__ __launch_bounds__(256) void k_count(const int* __restrict__ edges,
                                               int* __restrict__ cnt) {
    int i = blockIdx.x * 256 + threadIdx.x;
    if (i < E) atomicAdd(&cnt[edges[2 * i + 1]], 1);
}

__global__ __launch_bounds__(256) void k_scan(const int* __restrict__ cnt,
                                              int* __restrict__ offs) {
    __shared__ int part[256];
    int t = threadIdx.x;
    const int CH = 20;
    int base = t * CH;
    int s = 0;
    for (int i = 0; i < CH; ++i) { int idx = base + i; if (idx < N) s += cnt[idx]; }
    part[t] = s;
    __syncthreads();
    for (int off = 1; off < 256; off <<= 1) {
        int add = (t >= off) ? part[t - off] : 0;
        __syncthreads();
        part[t] += add;
        __syncthreads();
    }
    int run = part[t] - s;
    for (int i = 0; i < CH; ++i) {
        int idx = base + i;
        if (idx < N) { offs[idx] = run; run += cnt[idx]; }
    }
    if (t == 255) offs[N] = run;
}

__global__ __launch_bounds__(256) void k_fill(const int* __restrict__ edges,
                                              const int* __restrict__ offs,
                                              int* __restrict__ cursor,
                                              int* __restrict__ elist) {
    int i = blockIdx.x * 256 + threadIdx.x;
    if (i < E) {
        int child = edges[2 * i + 1];
        int pos = offs[child] + atomicAdd(&cursor[child], 1);
        elist[pos] = edges[2 * i];
    }
}

// ---------------- prepare (conv1 only): M = elu(elu(h @ W1) @ W2) ----------------
__global__ __launch_bounds__(512) void k_prepare(const float* __restrict__ xsrc,
                                                 const float* __restrict__ emb,
                                                 const float* __restrict__ hin,
                                                 const float* __restrict__ W1,
                                                 const float* __restrict__ W2,
                                                 float* __restrict__ M,
                                                 float* __restrict__ hwt) {
    __shared__ float sW1[64 * 64];      // 16 KB
    __shared__ float sP[128 * 65];      // 33.3 KB
    int t = threadIdx.x;
    int r0 = blockIdx.x * 128;
    for (int i = t; i < 4096; i += 512) sW1[i] = W1[i];
    if (xsrc) {
        for (int i = t; i < 128 * 64; i += 512) {
            int r = i >> 6, c = i & 63;
            int row = r0 + r;
            float v = 0.0f;
            if (row < BN) {
                int n = row % N;
                v = xsrc[row] * emb[n * 64 + c];
                hwt[(long)row * 64 + c] = v;
            }
            sP[r * 65 + c] = v;
        }
    } else {
        for (int i = t; i < 128 * 64; i += 512) {
            int r = i >> 6, c = i & 63;
            int row = r0 + r;
            sP[r * 65 + c] = (row < BN) ? hin[(long)row * 64 + c] : 0.0f;
        }
    }
    __syncthreads();

    int cg = t & 15, rg = t >> 4;
    float acc[4][4] = {};
    #pragma unroll 4
    for (int k = 0; k < 64; ++k) {
        float a[4];
        #pragma unroll
        for (int i = 0; i < 4; ++i) a[i] = sP[(rg * 4 + i) * 65 + k];
        float4 bb = *reinterpret_cast<const float4*>(&sW1[k * 64 + cg * 4]);
        #pragma unroll
        for (int i = 0; i < 4; ++i) {
            acc[i][0] += a[i] * bb.x; acc[i][1] += a[i] * bb.y;
            acc[i][2] += a[i] * bb.z; acc[i][3] += a[i] * bb.w;
        }
    }
    __syncthreads();
    #pragma unroll
    for (int i = 0; i < 4; ++i)
        #pragma unroll
        for (int j = 0; j < 4; ++j)
            sP[(rg * 4 + i) * 65 + cg * 4 + j] = elu_f(acc[i][j]);
    __syncthreads();

    float acc2[4][4] = {};
    #pragma unroll 4
    for (int k = 0; k < 64; ++k) {
        float a[4];
        #pragma unroll
        for (int i = 0; i < 4; ++i) a[i] = sP[(rg * 4 + i) * 65 + k];
        float4 bb = *reinterpret_cast<const float4*>(&W2[k * 64 + cg * 4]);
        #pragma unroll
        for (int i = 0; i < 4; ++i) {
            acc2[i][0] += a[i] * bb.x; acc2[i][1] += a[i] * bb.y;
            acc2[i][2] += a[i] * bb.z; acc2[i][3] += a[i] * bb.w;
        }
    }
    #pragma unroll
    for (int i = 0; i < 4; ++i) {
        int row = r0 + rg * 4 + i;
        if (row < BN) {
            float4 o = make_float4(elu_f(acc2[i][0]), elu_f(acc2[i][1]),
                                   elu_f(acc2[i][2]), elu_f(acc2[i][3]));
            *reinterpret_cast<float4*>(&M[(long)row * 64 + cg * 4]) = o;
        }
    }
}

// ---------------- fused conv: gather + update FFN (+ optional next-prepare) ----
// Per block: 64 rows (r0..r0+64). Phases:
//  A) stage W1u (LDS) + h rows -> sP[:,0:64); gather M rows -> sP[:,64:128)
//  B) GEMM1 (k=0..128) -> elu(+b1) -> sP[:,0:64); stage W1p|W2p into dead sW
//  C) GEMM2 (k=0..64, W2u from global) + b2 -> hout; PREP: also -> sP[:,64:128)
//  D) PREP: p1 = elu(row @ W1p) -> sP[:,0:64); p2: Mout = elu(p1 @ W2p)
template <int PREP>
__global__ __launch_bounds__(512) void k_conv(const float* __restrict__ h,
                                              const float* __restrict__ M,
                                              const int* __restrict__ offs,
                                              const int* __restrict__ elist,
                                              const float* __restrict__ W1u,  // [128][64]
                                              const float* __restrict__ b1u,
                                              const float* __restrict__ W2u,  // [64][64]
                                              const float* __restrict__ b2u,
                                              float* __restrict__ hout,
                                              const float* __restrict__ W1p,  // [64][64]
                                              const float* __restrict__ W2p,  // [64][64]
                                              float* __restrict__ Mout) {
    __shared__ float sW[128 * 64];      // 32 KB (W1u, later W1p|W2p)
    __shared__ float sP[64 * 129];      // 33 KB
    int t = threadIdx.x;
    long r0 = (long)blockIdx.x * 64;

    // A1: stage W1u (2048 float4)
    for (int q = t; q < 2048; q += 512)
        *reinterpret_cast<float4*>(&sW[q * 4]) =
            *reinterpret_cast<const float4*>(&W1u[q * 4]);
    // A2: stage h rows -> sP cols [0,64)
    for (int s = t; s < 64 * 16; s += 512) {
        int r = s >> 4, c4 = s & 15;
        float4 v = *reinterpret_cast<const float4*>(&h[(r0 + r) * 64 + c4 * 4]);
        int base = r * 129 + c4 * 4;
        sP[base + 0] = v.x; sP[base + 1] = v.y;
        sP[base + 2] = v.z; sP[base + 3] = v.w;
    }
    // A3: gather agg rows -> sP cols [64,128)
    {
        int wv = t >> 6, lane = t & 63;
        int h4 = lane & 15, le = lane >> 4;
        for (int rr = 0; rr < 8; ++rr) {
            int r = wv * 8 + rr;
            long row = r0 + r;
            int b = (int)(row / N);
            int n = (int)(row - (long)b * N);
            int e0 = offs[n], e1 = offs[n + 1];
            const float* Mb = M + (long)b * ND;
            float4 a = make_float4(0.f, 0.f, 0.f, 0.f);
            for (int e = e0 + le; e < e1; e += 4) {
                int p = elist[e];
                float4 v = *reinterpret_cast<const float4*>(&Mb[(long)p * 64 + h4 * 4]);
                a.x += v.x; a.y += v.y; a.z += v.z; a.w += v.w;
            }
            #pragma unroll
            for (int m = 16; m <= 32; m <<= 1) {
                a.x += __shfl_xor(a.x, m);
                a.y += __shfl_xor(a.y, m);
                a.z += __shfl_xor(a.z, m);
                a.w += __shfl_xor(a.w, m);
            }
            if (le == 0) {
                int base = r * 129 + 64 + h4 * 4;
                sP[base + 0] = a.x; sP[base + 1] = a.y;
                sP[base + 2] = a.z; sP[base + 3] = a.w;
            }
        }
    }
    __syncthreads();

    int cg = t & 15, rg = t >> 4;
    // B: update GEMM1 over k=0..128
    float acc[2][4] = {};
    #pragma unroll 4
    for (int k = 0; k < 128; ++k) {
        float a0 = sP[(rg * 2 + 0) * 129 + k];
        float a1 = sP[(rg * 2 + 1) * 129 + k];
        float4 bb = *reinterpret_cast<const float4*>(&sW[k * 64 + cg * 4]);
        acc[0][0] += a0 * bb.x; acc[0][1] += a0 * bb.y; acc[0][2] += a0 * bb.z; acc[0][3] += a0 * bb.w;
        acc[1][0] += a1 * bb.x; acc[1][1] += a1 * bb.y; acc[1][2] += a1 * bb.z; acc[1][3] += a1 * bb.w;
    }
    float4 bv1 = *reinterpret_cast<const float4*>(&b1u[cg * 4]);
    __syncthreads();
    #pragma unroll
    for (int i = 0; i < 2; ++i) {
        int base = (rg * 2 + i) * 129 + cg * 4;
        sP[base + 0] = elu_f(acc[i][0] + bv1.x);
        sP[base + 1] = elu_f(acc[i][1] + bv1.y);
        sP[base + 2] = elu_f(acc[i][2] + bv1.z);
        sP[base + 3] = elu_f(acc[i][3] + bv1.w);
    }
    if (PREP) {  // stage W1p (first 4096 floats) | W2p (next 4096) into dead sW
        for (int q = t; q < 2048; q += 512) {
            const float* src = (q < 1024) ? &W1p[q * 4] : &W2p[(q - 1024) * 4];
            *reinterpret_cast<float4*>(&sW[q * 4]) =
                *reinterpret_cast<const float4*>(src);
        }
    }
    __syncthreads();

    // C: update GEMM2 over k=0..64 (W2u from global)
    float acc2[2][4] = {};
    #pragma unroll 4
    for (int k = 0; k < 64; ++k) {
        float a0 = sP[(rg * 2 + 0) * 129 + k];
        float a1 = sP[(rg * 2 + 1) * 129 + k];
        float4 bb = *reinterpret_cast<const float4*>(&W2u[k * 64 + cg * 4]);
        acc2[0][0] += a0 * bb.x; acc2[0][1] += a0 * bb.y; acc2[0][2] += a0 * bb.z; acc2[0][3] += a0 * bb.w;
        acc2[1][0] += a1 * bb.x; acc2[1][1] += a1 * bb.y; acc2[1][2] += a1 * bb.z; acc2[1][3] += a1 * bb.w;
    }
    float4 bv2 = *reinterpret_cast<const float4*>(&b2u[cg * 4]);
    #pragma unroll
    for (int i = 0; i < 2; ++i) {
        float4 o = make_float4(acc2[i][0] + bv2.x, acc2[i][1] + bv2.y,
                               acc2[i][2] + bv2.z, acc2[i][3] + bv2.w);
        *reinterpret_cast<float4*>(&hout[(r0 + rg * 2 + i) * 64 + cg * 4]) = o;
        if (PREP) {  // also stash into sP cols [64,128) (disjoint from GEMM2 reads)
            int base = (rg * 2 + i) * 129 + 64 + cg * 4;
            sP[base + 0] = o.x; sP[base + 1] = o.y;
            sP[base + 2] = o.z; sP[base + 3] = o.w;
        }
    }

    if (PREP) {
        __syncthreads();
        // D1: p1 = elu(rows @ W1p), reads sP cols [64,128), W1p at sW[0..4096)
        float acc3[2][4] = {};
        #pragma unroll 4
        for (int k = 0; k < 64; ++k) {
            float a0 = sP[(rg * 2 + 0) * 129 + 64 + k];
            float a1 = sP[(rg * 2 + 1) * 129 + 64 + k];
            float4 bb = *reinterpret_cast<const float4*>(&sW[k * 64 + cg * 4]);
            acc3[0][0] += a0 * bb.x; acc3[0][1] += a0 * bb.y; acc3[0][2] += a0 * bb.z; acc3[0][3] += a0 * bb.w;
            acc3[1][0] += a1 * bb.x; acc3[1][1] += a1 * bb.y; acc3[1][2] += a1 * bb.z; acc3[1][3] += a1 * bb.w;
        }
        // write p1 into sP cols [0,64) (disjoint from p1 reads at cols>=64)
        #pragma unroll
        for (int i = 0; i < 2; ++i) {
            int base = (rg * 2 + i) * 129 + cg * 4;
            sP[base + 0] = elu_f(acc3[i][0]);
            sP[base + 1] = elu_f(acc3[i][1]);
            sP[base + 2] = elu_f(acc3[i][2]);
            sP[base + 3] = elu_f(acc3[i][3]);
        }
        __syncthreads();
        // D2: Mout = elu(p1 @ W2p), W2p at sW[4096..8192)
        float acc4[2][4] = {};
        #pragma unroll 4
        for (int k = 0; k < 64; ++k) {
            float a0 = sP[(rg * 2 + 0) * 129 + k];
            float a1 = sP[(rg * 2 + 1) * 129 + k];
            float4 bb = *reinterpret_cast<const float4*>(&sW[4096 + k * 64 + cg * 4]);
            acc4[0][0] += a0 * bb.x; acc4[0][1] += a0 * bb.y; acc4[0][2] += a0 * bb.z; acc4[0][3] += a0 * bb.w;
            acc4[1][0] += a1 * bb.x; acc4[1][1] += a1 * bb.y; acc4[1][2] += a1 * bb.z; acc4[1][3] += a1 * bb.w;
        }
        #pragma unroll
        for (int i = 0; i < 2; ++i) {
            float4 o = make_float4(elu_f(acc4[i][0]), elu_f(acc4[i][1]),
                                   elu_f(acc4[i][2]), elu_f(acc4[i][3]));
            *reinterpret_cast<float4*>(&Mout[(r0 + rg * 2 + i) * 64 + cg * 4]) = o;
        }
    }
}

// ---------------- partial[yb,xb,:] = per-block head GEMV partial ----------------
// R6 version, unchanged: 8-slot LDS ring via global_load_lds, counted vmcnt(7).
__global__ __launch_bounds__(256) void k_head(const float* __restrict__ phi,   // [8][ND]
                                              const float* __restrict__ w0a,
                                              const float* __restrict__ w1a,
                                              float* __restrict__ part) {      // [2][XB][1024]
    __shared__ float smem[4 * 32 * 33];              // 16.9 KB; phi chunk + partials
    __shared__ __align__(16) float wb[8][1024];      // 32 KB ring (8 x 4KB)
    const float* wa = blockIdx.y ? w1a : w0a;
    int t = threadIdx.x;
    int k0 = blockIdx.x * KC;

    #pragma unroll
    for (int b = 0; b < 8; ++b)
        for (int kk = t; kk < KC; kk += 256)
            smem[b * KC + kk] = phi[(long)b * ND + k0 + kk];
    __syncthreads();

    int w = t >> 6, l = t & 63;
    int h4 = l & 31, kh = l >> 5;
    int kl = w * 2 + kh;                       // [0,8)
    const float* wp = wa + (long)(k0 + kl) * H + h4 * 4;

    float4 acc[8];
    #pragma unroll
    for (int b = 0; b < 8; ++b) acc[b] = make_float4(0.f, 0.f, 0.f, 0.f);

    unsigned my_off =
        (unsigned)(size_t)(__attribute__((address_space(3))) float*)&wb[0][0]
        + (unsigned)t * 16u;

    const float* wq = wp;
    #pragma unroll
    for (int j = 0; j < 8; ++j) {
        g2lds16(wq, &wb[j][w * 256]);
        wq += 8 * H;
    }

#define STEP(I, CNT, OFF, RE)                                              \
    {                                                                      \
        asm volatile("s_waitcnt vmcnt(" #CNT ")" ::: "memory");            \
        __builtin_amdgcn_sched_barrier(0);                                 \
        f32x4 w4;                                                          \
        asm volatile("ds_read_b128 %0, %1 offset:" #OFF                    \
                     : "=v"(w4) : "v"(my_off));                            \
        float pv[8];                                                       \
        _Pragma("unroll")                                                  \
        for (int b = 0; b < 8; ++b)                                        \
            pv[b] = smem[b * KC + (I) * 8 + kl];                           \
        asm volatile("s_waitcnt lgkmcnt(0)" ::: "memory");                 \
        __builtin_amdgcn_sched_barrier(0);                                 \
        _Pragma("unroll")                                                  \
        for (int b = 0; b < 8; ++b) {                                      \
            acc[b].x += pv[b] * w4.x; acc[b].y += pv[b] * w4.y;            \
            acc[b].z += pv[b] * w4.z; acc[b].w += pv[b] * w4.w;            \
        }                                                                  \
        if (RE) {                                                          \
            g2lds16(wq, &wb[(I) & 7][w * 256]);                            \
            wq += 8 * H;                                                   \
        }                                                                  \
    }

#define ROUND8(BASE, RE)                                                   \
    STEP(BASE + 0, 7, 0,     RE) STEP(BASE + 1, 7, 4096,  RE)              \
    STEP(BASE + 2, 7, 8192,  RE) STEP(BASE + 3, 7, 12288, RE)              \
    STEP(BASE + 4, 7, 16384, RE) STEP(BASE + 5, 7, 20480, RE)              \
    STEP(BASE + 6, 7, 24576, RE) STEP(BASE + 7, 7, 28672, RE)

    ROUND8(0, 1) ROUND8(8, 1) ROUND8(16, 1) ROUND8(24, 1)
    STEP(32, 7, 0,     0) STEP(33, 6, 4096,  0)
    STEP(34, 5, 8192,  0) STEP(35, 4, 12288, 0)
    STEP(36, 3, 16384, 0) STEP(37, 2, 20480, 0)
    STEP(38, 1, 24576, 0) STEP(39, 0, 28672, 0)
#undef ROUND8
#undef STEP

    #pragma unroll
    for (int b = 0; b < 8; ++b) {
        acc[b].x += __shfl_xor(acc[b].x, 32);
        acc[b].y += __shfl_xor(acc[b].y, 32);
        acc[b].z += __shfl_xor(acc[b].z, 32);
        acc[b].w += __shfl_xor(acc[b].w, 32);
    }
    __syncthreads();   // phi reads done; smem reused for partials
    if (kh == 0) {
        int base = (w * 32 + h4) * 33;
        #pragma unroll
        for (int b = 0; b < 8; ++b) {
            smem[base + b * 4 + 0] = acc[b].x;
            smem[base + b * 4 + 1] = acc[b].y;
            smem[base + b * 4 + 2] = acc[b].z;
            smem[base + b * 4 + 3] = acc[b].w;
        }
    }
    __syncthreads();

    int h4r = t & 31, br = t >> 5;
    float s0 = 0.f, s1 = 0.f, s2 = 0.f, s3 = 0.f;
    #pragma unroll
    for (int wv = 0; wv < 4; ++wv) {
        int idx = (wv * 32 + h4r) * 33 + br * 4;
        s0 += smem[idx + 0]; s1 += smem[idx + 1];
        s2 += smem[idx + 2]; s3 += smem[idx + 3];
    }
    float* pb = part + ((long)blockIdx.y * XB + blockIdx.x) * 1024;
    *reinterpret_cast<float4*>(&pb[br * H + h4r * 4]) =
        make_float4(s0, s1, s2, s3);
}

// ---------------- hidden[y*1024+j] = sum_x part[y,x,j] ----------------
__global__ __launch_bounds__(256) void k_reduce(const float* __restrict__ part,
                                                float* __restrict__ hidden) {
    int idx = blockIdx.x * 256 + threadIdx.x;      // [0, 2048)
    int c = blockIdx.y;                            // [0, 16)
    int y = idx >> 10, j = idx & 1023;
    const float* p = part + (long)y * XB * 1024 + j;
    int x0 = (XB * c) >> 4, x1 = (XB * (c + 1)) >> 4;
    float s0 = 0.f, s1 = 0.f, s2 = 0.f, s3 = 0.f;
    int x = x0;
    for (; x + 3 < x1; x += 4) {
        s0 += p[(long)(x + 0) * 1024];
        s1 += p[(long)(x + 1) * 1024];
        s2 += p[(long)(x + 2) * 1024];
        s3 += p[(long)(x + 3) * 1024];
    }
    for (; x < x1; ++x) s0 += p[(long)x * 1024];
    unsafeAtomicAdd(&hidden[y * 1024 + j], s0 + s1 + s2 + s3);
}

// ---------------- out[b, head*2+j] = elu(hidden+ba) @ wb + bb ----------------
__global__ __launch_bounds__(64) void k_final(const float* __restrict__ hidden,
                                              const float* __restrict__ b0a,
                                              const float* __restrict__ w0b,
                                              const float* __restrict__ b0b,
                                              const float* __restrict__ b1a,
                                              const float* __restrict__ w1b,
                                              const float* __restrict__ b1b,
                                              float* __restrict__ out) {
    int t = threadIdx.x;
    if (t >= 32) return;
    int head = t >> 4, b = (t >> 1) & 7, j = t & 1;
    const float* hid = hidden + head * (8 * H) + b * H;
    const float* ba = head ? b1a : b0a;
    const float* wb = head ? w1b : w0b;
    const float* bb = head ? b1b : b0b;
    float acc = 0.0f;
    for (int hh = 0; hh < H; ++hh)
        acc += elu_f(hid[hh] + ba[hh]) * wb[hh * 2 + j];
    out[b * 4 + head * 2 + j] = acc + bb[j];
}

extern "C" void kernel_launch(void* const* d_in, const int* in_sizes, int n_in,
                              void* d_out, int out_size, void* d_ws, size_t ws_size,
                              hipStream_t stream) {
    const float* x      = (const float*)d_in[0];
    const int*   edges  = (const int*)d_in[1];
    const float* emb    = (const float*)d_in[2];
    const float* c1_pw1 = (const float*)d_in[3];
    const float* c1_pw2 = (const float*)d_in[4];
    const float* c1_uw1 = (const float*)d_in[5];
    const float* c1_ub1 = (const float*)d_in[6];
    const float* c1_uw2 = (const float*)d_in[7];
    const float* c1_ub2 = (const float*)d_in[8];
    const float* c2_pw1 = (const float*)d_in[9];
    const float* c2_pw2 = (const float*)d_in[10];
    const float* c2_uw1 = (const float*)d_in[11];
    const float* c2_ub1 = (const float*)d_in[12];
    const float* c2_uw2 = (const float*)d_in[13];
    const float* c2_ub2 = (const float*)d_in[14];
    const float* w0a    = (const float*)d_in[15];
    const float* b0a    = (const float*)d_in[16];
    const float* w0b    = (const float*)d_in[17];
    const float* b0b    = (const float*)d_in[18];
    const float* w1a    = (const float*)d_in[19];
    const float* b1a    = (const float*)d_in[20];
    const float* w1b    = (const float*)d_in[21];
    const float* b1b    = (const float*)d_in[22];
    float* out = (float*)d_out;

    float* hA     = (float*)d_ws;          // [BN, D]
    float* hB     = hA + BND;
    float* Mu     = hB + BND;              // conv1 messages; aliased as `part`
    float* M2     = Mu + BND;              // conv2 messages (old agg slot)
    float* hidden = M2 + BND;              // [2][8][H] = 2048 floats
    int* cnt      = (int*)(hidden + 2048); // [N]
    int* cursor   = cnt + N;               // [N]
    int* offs     = cursor + N;            // [N+1]
    int* elist    = offs + N + 1;          // [E]
    float* part   = Mu;                    // [2][XB][1024] = 2.048M floats <= BND

    hipMemsetAsync(hidden, 0, (2048 + 2 * N) * sizeof(float), stream);

    k_count<<<(E + 255) / 256, 256, 0, stream>>>(edges, cnt);
    k_scan<<<1, 256, 0, stream>>>(cnt, offs);
    k_fill<<<(E + 255) / 256, 256, 0, stream>>>(edges, offs, cursor, elist);

    // conv1 prepare (also materializes hA = x*emb)
    k_prepare<<<(BN + 127) / 128, 512, 0, stream>>>(x, emb, nullptr, c1_pw1, c1_pw2, Mu, hA);
    // conv1 gather+update, fused with conv2 prepare (writes hB and M2)
    k_conv<1><<<BN / 64, 512, 0, stream>>>(hA, Mu, offs, elist,
                                           c1_uw1, c1_ub1, c1_uw2, c1_ub2, hB,
                                           c2_pw1, c2_pw2, M2);
    // conv2 gather+update (writes hA = phi)
    k_conv<0><<<BN / 64, 512, 0, stream>>>(hB, M2, offs, elist,
                                           c2_uw1, c2_ub1, c2_uw2, c2_ub2, hA,
                                           nullptr, nullptr, nullptr);

    // heads: partials (Mu is dead scratch by now) -> reduce -> final
    k_head<<<dim3(XB, 2), 256, 0, stream>>>(hA, w0a, w1a, part);
    k_reduce<<<dim3(8, 16), 256, 0, stream>>>(part, hidden);
    k_final<<<1, 64, 0, stream>>>(hidden, b0a, w0b, b0b, b1a, w1b, b1b, out);
}

// Round 4
// 630.476 us; speedup vs baseline: 1.0913x; 1.0913x over previous
//
#include <hip/hip_runtime.h>

// GNN TARnet: h = x*emb -> 2x graph conv -> two prob heads.
// R8: k_conv slimmed for gather-latency hiding. No weight staging in LDS
//     (W1u is 32KB = L1-resident; rows are broadcast reads) -> LDS 66->33KB
//     -> 4 blocks/CU (32 waves, was 16). Gather edge-loop unrolled x2 for
//     2x outstanding loads/lane. __launch_bounds__(512,8) pins VGPR<=64.
//     Everything else byte-identical to R7 (k_head at its ~3TB/s wall).

constexpr int B = 8, N = 5000, E = 160000, D = 64, H = 128;
constexpr int BN = B * N;           // 40000
constexpr int ND = N * D;           // 320000
constexpr long BND = (long)BN * D;  // 2,560,000
constexpr int KC = 320;             // k-chunk per head block
constexpr int NIT = KC / 8;         // 40 k-iters per thread
constexpr int XB = ND / KC;         // 1000 x-blocks per head

using f32x4 = __attribute__((ext_vector_type(4))) float;

__device__ __forceinline__ float elu_f(float x) {
    return x > 0.0f ? x : __expf(x) - 1.0f;
}

__device__ __forceinline__ void g2lds16(const float* g, float* l) {
    __builtin_amdgcn_global_load_lds(
        (const __attribute__((address_space(1))) void*)g,
        (__attribute__((address_space(3))) void*)l, 16, 0, 0);
}

// ---------------- CSR build (edges grouped by child) ----------------
__global__ __launch_bounds__(256) void k_count(const int* __restrict__ edges,
                                               int* __restrict__ cnt) {
    int i = blockIdx.x * 256 + threadIdx.x;
    if (i < E) atomicAdd(&cnt[edges[2 * i + 1]], 1);
}

__global__ __launch_bounds__(256) void k_scan(const int* __restrict__ cnt,
                                              int* __restrict__ offs) {
    __shared__ int part[256];
    int t = threadIdx.x;
    const int CH = 20;
    int base = t * CH;
    int s = 0;
    for (int i = 0; i < CH; ++i) { int idx = base + i; if (idx < N) s += cnt[idx]; }
    part[t] = s;
    __syncthreads();
    for (int off = 1; off < 256; off <<= 1) {
        int add = (t >= off) ? part[t - off] : 0;
        __syncthreads();
        part[t] += add;
        __syncthreads();
    }
    int run = part[t] - s;
    for (int i = 0; i < CH; ++i) {
        int idx = base + i;
        if (idx < N) { offs[idx] = run; run += cnt[idx]; }
    }
    if (t == 255) offs[N] = run;
}

__global__ __launch_bounds__(256) void k_fill(const int* __restrict__ edges,
                                              const int* __restrict__ offs,
                                              int* __restrict__ cursor,
                                              int* __restrict__ elist) {
    int i = blockIdx.x * 256 + threadIdx.x;
    if (i < E) {
        int child = edges[2 * i + 1];
        int pos = offs[child] + atomicAdd(&cursor[child], 1);
        elist[pos] = edges[2 * i];
    }
}

// ---------------- prepare (conv1 only): M = elu(elu(h @ W1) @ W2) ----------------
__global__ __launch_bounds__(512) void k_prepare(const float* __restrict__ xsrc,
                                                 const float* __restrict__ emb,
                                                 const float* __restrict__ hin,
                                                 const float* __restrict__ W1,
                                                 const float* __restrict__ W2,
                                                 float* __restrict__ M,
                                                 float* __restrict__ hwt) {
    __shared__ float sW1[64 * 64];      // 16 KB
    __shared__ float sP[128 * 65];      // 33.3 KB
    int t = threadIdx.x;
    int r0 = blockIdx.x * 128;
    for (int i = t; i < 4096; i += 512) sW1[i] = W1[i];
    if (xsrc) {
        for (int i = t; i < 128 * 64; i += 512) {
            int r = i >> 6, c = i & 63;
            int row = r0 + r;
            float v = 0.0f;
            if (row < BN) {
                int n = row % N;
                v = xsrc[row] * emb[n * 64 + c];
                hwt[(long)row * 64 + c] = v;
            }
            sP[r * 65 + c] = v;
        }
    } else {
        for (int i = t; i < 128 * 64; i += 512) {
            int r = i >> 6, c = i & 63;
            int row = r0 + r;
            sP[r * 65 + c] = (row < BN) ? hin[(long)row * 64 + c] : 0.0f;
        }
    }
    __syncthreads();

    int cg = t & 15, rg = t >> 4;
    float acc[4][4] = {};
    #pragma unroll 4
    for (int k = 0; k < 64; ++k) {
        float a[4];
        #pragma unroll
        for (int i = 0; i < 4; ++i) a[i] = sP[(rg * 4 + i) * 65 + k];
        float4 bb = *reinterpret_cast<const float4*>(&sW1[k * 64 + cg * 4]);
        #pragma unroll
        for (int i = 0; i < 4; ++i) {
            acc[i][0] += a[i] * bb.x; acc[i][1] += a[i] * bb.y;
            acc[i][2] += a[i] * bb.z; acc[i][3] += a[i] * bb.w;
        }
    }
    __syncthreads();
    #pragma unroll
    for (int i = 0; i < 4; ++i)
        #pragma unroll
        for (int j = 0; j < 4; ++j)
            sP[(rg * 4 + i) * 65 + cg * 4 + j] = elu_f(acc[i][j]);
    __syncthreads();

    float acc2[4][4] = {};
    #pragma unroll 4
    for (int k = 0; k < 64; ++k) {
        float a[4];
        #pragma unroll
        for (int i = 0; i < 4; ++i) a[i] = sP[(rg * 4 + i) * 65 + k];
        float4 bb = *reinterpret_cast<const float4*>(&W2[k * 64 + cg * 4]);
        #pragma unroll
        for (int i = 0; i < 4; ++i) {
            acc2[i][0] += a[i] * bb.x; acc2[i][1] += a[i] * bb.y;
            acc2[i][2] += a[i] * bb.z; acc2[i][3] += a[i] * bb.w;
        }
    }
    #pragma unroll
    for (int i = 0; i < 4; ++i) {
        int row = r0 + rg * 4 + i;
        if (row < BN) {
            float4 o = make_float4(elu_f(acc2[i][0]), elu_f(acc2[i][1]),
                                   elu_f(acc2[i][2]), elu_f(acc2[i][3]));
            *reinterpret_cast<float4*>(&M[(long)row * 64 + cg * 4]) = o;
        }
    }
}

// ---------------- fused conv: gather + update FFN (+ optional next-prepare) ----
// R8: LDS = sP only (33 KB) -> 4 blocks/CU. All weight rows read from global
// (broadcast per 16-lane group; W1u = 32 KB fits L1). Gather unrolled x2.
template <int PREP>
__global__ __launch_bounds__(512, 8) void k_conv(const float* __restrict__ h,
                                                 const float* __restrict__ M,
                                                 const int* __restrict__ offs,
                                                 const int* __restrict__ elist,
                                                 const float* __restrict__ W1u,  // [128][64]
                                                 const float* __restrict__ b1u,
                                                 const float* __restrict__ W2u,  // [64][64]
                                                 const float* __restrict__ b2u,
                                                 float* __restrict__ hout,
                                                 const float* __restrict__ W1p,  // [64][64]
                                                 const float* __restrict__ W2p,  // [64][64]
                                                 float* __restrict__ Mout) {
    __shared__ float sP[64 * 129];      // 33 KB
    int t = threadIdx.x;
    long r0 = (long)blockIdx.x * 64;

    // A1: stage h rows -> sP cols [0,64)
    for (int s = t; s < 64 * 16; s += 512) {
        int r = s >> 4, c4 = s & 15;
        float4 v = *reinterpret_cast<const float4*>(&h[(r0 + r) * 64 + c4 * 4]);
        int base = r * 129 + c4 * 4;
        sP[base + 0] = v.x; sP[base + 1] = v.y;
        sP[base + 2] = v.z; sP[base + 3] = v.w;
    }
    // A2: gather agg rows -> sP cols [64,128); edge loop unrolled x2
    {
        int wv = t >> 6, lane = t & 63;
        int h4 = lane & 15, le = lane >> 4;
        for (int rr = 0; rr < 8; ++rr) {
            int r = wv * 8 + rr;
            long row = r0 + r;
            int b = (int)(row / N);
            int n = (int)(row - (long)b * N);
            int e0 = offs[n], e1 = offs[n + 1];
            const float* Mb = M + (long)b * ND;
            float4 a = make_float4(0.f, 0.f, 0.f, 0.f);
            float4 a2 = make_float4(0.f, 0.f, 0.f, 0.f);
            int e = e0 + le;
            for (; e + 4 < e1; e += 8) {
                int p1 = elist[e];
                int p2 = elist[e + 4];
                float4 v1 = *reinterpret_cast<const float4*>(&Mb[(long)p1 * 64 + h4 * 4]);
                float4 v2 = *reinterpret_cast<const float4*>(&Mb[(long)p2 * 64 + h4 * 4]);
                a.x += v1.x; a.y += v1.y; a.z += v1.z; a.w += v1.w;
                a2.x += v2.x; a2.y += v2.y; a2.z += v2.z; a2.w += v2.w;
            }
            if (e < e1) {
                int p = elist[e];
                float4 v = *reinterpret_cast<const float4*>(&Mb[(long)p * 64 + h4 * 4]);
                a.x += v.x; a.y += v.y; a.z += v.z; a.w += v.w;
            }
            a.x += a2.x; a.y += a2.y; a.z += a2.z; a.w += a2.w;
            #pragma unroll
            for (int m = 16; m <= 32; m <<= 1) {
                a.x += __shfl_xor(a.x, m);
                a.y += __shfl_xor(a.y, m);
                a.z += __shfl_xor(a.z, m);
                a.w += __shfl_xor(a.w, m);
            }
            if (le == 0) {
                int base = r * 129 + 64 + h4 * 4;
                sP[base + 0] = a.x; sP[base + 1] = a.y;
                sP[base + 2] = a.z; sP[base + 3] = a.w;
            }
        }
    }
    __syncthreads();

    int cg = t & 15, rg = t >> 4;
    // B: update GEMM1 over k=0..128 (W1u rows broadcast from global/L1)
    float acc[2][4] = {};
    #pragma unroll 4
    for (int k = 0; k < 128; ++k) {
        float a0 = sP[(rg * 2 + 0) * 129 + k];
        float a1 = sP[(rg * 2 + 1) * 129 + k];
        float4 bb = *reinterpret_cast<const float4*>(&W1u[k * 64 + cg * 4]);
        acc[0][0] += a0 * bb.x; acc[0][1] += a0 * bb.y; acc[0][2] += a0 * bb.z; acc[0][3] += a0 * bb.w;
        acc[1][0] += a1 * bb.x; acc[1][1] += a1 * bb.y; acc[1][2] += a1 * bb.z; acc[1][3] += a1 * bb.w;
    }
    float4 bv1 = *reinterpret_cast<const float4*>(&b1u[cg * 4]);
    __syncthreads();
    #pragma unroll
    for (int i = 0; i < 2; ++i) {
        int base = (rg * 2 + i) * 129 + cg * 4;
        sP[base + 0] = elu_f(acc[i][0] + bv1.x);
        sP[base + 1] = elu_f(acc[i][1] + bv1.y);
        sP[base + 2] = elu_f(acc[i][2] + bv1.z);
        sP[base + 3] = elu_f(acc[i][3] + bv1.w);
    }
    __syncthreads();

    // C: update GEMM2 over k=0..64
    float acc2[2][4] = {};
    #pragma unroll 4
    for (int k = 0; k < 64; ++k) {
        float a0 = sP[(rg * 2 + 0) * 129 + k];
        float a1 = sP[(rg * 2 + 1) * 129 + k];
        float4 bb = *reinterpret_cast<const float4*>(&W2u[k * 64 + cg * 4]);
        acc2[0][0] += a0 * bb.x; acc2[0][1] += a0 * bb.y; acc2[0][2] += a0 * bb.z; acc2[0][3] += a0 * bb.w;
        acc2[1][0] += a1 * bb.x; acc2[1][1] += a1 * bb.y; acc2[1][2] += a1 * bb.z; acc2[1][3] += a1 * bb.w;
    }
    float4 bv2 = *reinterpret_cast<const float4*>(&b2u[cg * 4]);
    #pragma unroll
    for (int i = 0; i < 2; ++i) {
        float4 o = make_float4(acc2[i][0] + bv2.x, acc2[i][1] + bv2.y,
                               acc2[i][2] + bv2.z, acc2[i][3] + bv2.w);
        *reinterpret_cast<float4*>(&hout[(r0 + rg * 2 + i) * 64 + cg * 4]) = o;
        if (PREP) {  // stash into sP cols [64,128) (disjoint from GEMM2 reads)
            int base = (rg * 2 + i) * 129 + 64 + cg * 4;
            sP[base + 0] = o.x; sP[base + 1] = o.y;
            sP[base + 2] = o.z; sP[base + 3] = o.w;
        }
    }

    if (PREP) {
        __syncthreads();
        // D1: p1 = elu(rows @ W1p), reads sP cols [64,128)
        float acc3[2][4] = {};
        #pragma unroll 4
        for (int k = 0; k < 64; ++k) {
            float a0 = sP[(rg * 2 + 0) * 129 + 64 + k];
            float a1 = sP[(rg * 2 + 1) * 129 + 64 + k];
            float4 bb = *reinterpret_cast<const float4*>(&W1p[k * 64 + cg * 4]);
            acc3[0][0] += a0 * bb.x; acc3[0][1] += a0 * bb.y; acc3[0][2] += a0 * bb.z; acc3[0][3] += a0 * bb.w;
            acc3[1][0] += a1 * bb.x; acc3[1][1] += a1 * bb.y; acc3[1][2] += a1 * bb.z; acc3[1][3] += a1 * bb.w;
        }
        #pragma unroll
        for (int i = 0; i < 2; ++i) {
            int base = (rg * 2 + i) * 129 + cg * 4;
            sP[base + 0] = elu_f(acc3[i][0]);
            sP[base + 1] = elu_f(acc3[i][1]);
            sP[base + 2] = elu_f(acc3[i][2]);
            sP[base + 3] = elu_f(acc3[i][3]);
        }
        __syncthreads();
        // D2: Mout = elu(p1 @ W2p)
        float acc4[2][4] = {};
        #pragma unroll 4
        for (int k = 0; k < 64; ++k) {
            float a0 = sP[(rg * 2 + 0) * 129 + k];
            float a1 = sP[(rg * 2 + 1) * 129 + k];
            float4 bb = *reinterpret_cast<const float4*>(&W2p[k * 64 + cg * 4]);
            acc4[0][0] += a0 * bb.x; acc4[0][1] += a0 * bb.y; acc4[0][2] += a0 * bb.z; acc4[0][3] += a0 * bb.w;
            acc4[1][0] += a1 * bb.x; acc4[1][1] += a1 * bb.y; acc4[1][2] += a1 * bb.z; acc4[1][3] += a1 * bb.w;
        }
        #pragma unroll
        for (int i = 0; i < 2; ++i) {
            float4 o = make_float4(elu_f(acc4[i][0]), elu_f(acc4[i][1]),
                                   elu_f(acc4[i][2]), elu_f(acc4[i][3]));
            *reinterpret_cast<float4*>(&Mout[(r0 + rg * 2 + i) * 64 + cg * 4]) = o;
        }
    }
}

// ---------------- partial[yb,xb,:] = per-block head GEMV partial ----------------
// R6 version, unchanged: 8-slot LDS ring via global_load_lds, counted vmcnt(7).
__global__ __launch_bounds__(256) void k_head(const float* __restrict__ phi,   // [8][ND]
                                              const float* __restrict__ w0a,
                                              const float* __restrict__ w1a,
                                              float* __restrict__ part) {      // [2][XB][1024]
    __shared__ float smem[4 * 32 * 33];              // 16.9 KB; phi chunk + partials
    __shared__ __align__(16) float wb[8][1024];      // 32 KB ring (8 x 4KB)
    const float* wa = blockIdx.y ? w1a : w0a;
    int t = threadIdx.x;
    int k0 = blockIdx.x * KC;

    #pragma unroll
    for (int b = 0; b < 8; ++b)
        for (int kk = t; kk < KC; kk += 256)
            smem[b * KC + kk] = phi[(long)b * ND + k0 + kk];
    __syncthreads();

    int w = t >> 6, l = t & 63;
    int h4 = l & 31, kh = l >> 5;
    int kl = w * 2 + kh;                       // [0,8)
    const float* wp = wa + (long)(k0 + kl) * H + h4 * 4;

    float4 acc[8];
    #pragma unroll
    for (int b = 0; b < 8; ++b) acc[b] = make_float4(0.f, 0.f, 0.f, 0.f);

    unsigned my_off =
        (unsigned)(size_t)(__attribute__((address_space(3))) float*)&wb[0][0]
        + (unsigned)t * 16u;

    const float* wq = wp;
    #pragma unroll
    for (int j = 0; j < 8; ++j) {
        g2lds16(wq, &wb[j][w * 256]);
        wq += 8 * H;
    }

#define STEP(I, CNT, OFF, RE)                                              \
    {                                                                      \
        asm volatile("s_waitcnt vmcnt(" #CNT ")" ::: "memory");            \
        __builtin_amdgcn_sched_barrier(0);                                 \
        f32x4 w4;                                                          \
        asm volatile("ds_read_b128 %0, %1 offset:" #OFF                    \
                     : "=v"(w4) : "v"(my_off));                            \
        float pv[8];                                                       \
        _Pragma("unroll")                                                  \
        for (int b = 0; b < 8; ++b)                                        \
            pv[b] = smem[b * KC + (I) * 8 + kl];                           \
        asm volatile("s_waitcnt lgkmcnt(0)" ::: "memory");                 \
        __builtin_amdgcn_sched_barrier(0);                                 \
        _Pragma("unroll")                                                  \
        for (int b = 0; b < 8; ++b) {                                      \
            acc[b].x += pv[b] * w4.x; acc[b].y += pv[b] * w4.y;            \
            acc[b].z += pv[b] * w4.z; acc[b].w += pv[b] * w4.w;            \
        }                                                                  \
        if (RE) {                                                          \
            g2lds16(wq, &wb[(I) & 7][w * 256]);                            \
            wq += 8 * H;                                                   \
        }                                                                  \
    }

#define ROUND8(BASE, RE)                                                   \
    STEP(BASE + 0, 7, 0,     RE) STEP(BASE + 1, 7, 4096,  RE)              \
    STEP(BASE + 2, 7, 8192,  RE) STEP(BASE + 3, 7, 12288, RE)              \
    STEP(BASE + 4, 7, 16384, RE) STEP(BASE + 5, 7, 20480, RE)              \
    STEP(BASE + 6, 7, 24576, RE) STEP(BASE + 7, 7, 28672, RE)

    ROUND8(0, 1) ROUND8(8, 1) ROUND8(16, 1) ROUND8(24, 1)
    STEP(32, 7, 0,     0) STEP(33, 6, 4096,  0)
    STEP(34, 5, 8192,  0) STEP(35, 4, 12288, 0)
    STEP(36, 3, 16384, 0) STEP(37, 2, 20480, 0)
    STEP(38, 1, 24576, 0) STEP(39, 0, 28672, 0)
#undef ROUND8
#undef STEP

    #pragma unroll
    for (int b = 0; b < 8; ++b) {
        acc[b].x += __shfl_xor(acc[b].x, 32);
        acc[b].y += __shfl_xor(acc[b].y, 32);
        acc[b].z += __shfl_xor(acc[b].z, 32);
        acc[b].w += __shfl_xor(acc[b].w, 32);
    }
    __syncthreads();   // phi reads done; smem reused for partials
    if (kh == 0) {
        int base = (w * 32 + h4) * 33;
        #pragma unroll
        for (int b = 0; b < 8; ++b) {
            smem[base + b * 4 + 0] = acc[b].x;
            smem[base + b * 4 + 1] = acc[b].y;
            smem[base + b * 4 + 2] = acc[b].z;
            smem[base + b * 4 + 3] = acc[b].w;
        }
    }
    __syncthreads();

    int h4r = t & 31, br = t >> 5;
    float s0 = 0.f, s1 = 0.f, s2 = 0.f, s3 = 0.f;
    #pragma unroll
    for (int wv = 0; wv < 4; ++wv) {
        int idx = (wv * 32 + h4r) * 33 + br * 4;
        s0 += smem[idx + 0]; s1 += smem[idx + 1];
        s2 += smem[idx + 2]; s3 += smem[idx + 3];
    }
    float* pb = part + ((long)blockIdx.y * XB + blockIdx.x) * 1024;
    *reinterpret_cast<float4*>(&pb[br * H + h4r * 4]) =
        make_float4(s0, s1, s2, s3);
}

// ---------------- hidden[y*1024+j] = sum_x part[y,x,j] ----------------
__global__ __launch_bounds__(256) void k_reduce(const float* __restrict__ part,
                                                float* __restrict__ hidden) {
    int idx = blockIdx.x * 256 + threadIdx.x;      // [0, 2048)
    int c = blockIdx.y;                            // [0, 16)
    int y = idx >> 10, j = idx & 1023;
    const float* p = part + (long)y * XB * 1024 + j;
    int x0 = (XB * c) >> 4, x1 = (XB * (c + 1)) >> 4;
    float s0 = 0.f, s1 = 0.f, s2 = 0.f, s3 = 0.f;
    int x = x0;
    for (; x + 3 < x1; x += 4) {
        s0 += p[(long)(x + 0) * 1024];
        s1 += p[(long)(x + 1) * 1024];
        s2 += p[(long)(x + 2) * 1024];
        s3 += p[(long)(x + 3) * 1024];
    }
    for (; x < x1; ++x) s0 += p[(long)x * 1024];
    unsafeAtomicAdd(&hidden[y * 1024 + j], s0 + s1 + s2 + s3);
}

// ---------------- out[b, head*2+j] = elu(hidden+ba) @ wb + bb ----------------
__global__ __launch_bounds__(64) void k_final(const float* __restrict__ hidden,
                                              const float* __restrict__ b0a,
                                              const float* __restrict__ w0b,
                                              const float* __restrict__ b0b,
                                              const float* __restrict__ b1a,
                                              const float* __restrict__ w1b,
                                              const float* __restrict__ b1b,
                                              float* __restrict__ out) {
    int t = threadIdx.x;
    if (t >= 32) return;
    int head = t >> 4, b = (t >> 1) & 7, j = t & 1;
    const float* hid = hidden + head * (8 * H) + b * H;
    const float* ba = head ? b1a : b0a;
    const float* wb = head ? w1b : w0b;
    const float* bb = head ? b1b : b0b;
    float acc = 0.0f;
    for (int hh = 0; hh < H; ++hh)
        acc += elu_f(hid[hh] + ba[hh]) * wb[hh * 2 + j];
    out[b * 4 + head * 2 + j] = acc + bb[j];
}

extern "C" void kernel_launch(void* const* d_in, const int* in_sizes, int n_in,
                              void* d_out, int out_size, void* d_ws, size_t ws_size,
                              hipStream_t stream) {
    const float* x      = (const float*)d_in[0];
    const int*   edges  = (const int*)d_in[1];
    const float* emb    = (const float*)d_in[2];
    const float* c1_pw1 = (const float*)d_in[3];
    const float* c1_pw2 = (const float*)d_in[4];
    const float* c1_uw1 = (const float*)d_in[5];
    const float* c1_ub1 = (const float*)d_in[6];
    const float* c1_uw2 = (const float*)d_in[7];
    const float* c1_ub2 = (const float*)d_in[8];
    const float* c2_pw1 = (const float*)d_in[9];
    const float* c2_pw2 = (const float*)d_in[10];
    const float* c2_uw1 = (const float*)d_in[11];
    const float* c2_ub1 = (const float*)d_in[12];
    const float* c2_uw2 = (const float*)d_in[13];
    const float* c2_ub2 = (const float*)d_in[14];
    const float* w0a    = (const float*)d_in[15];
    const float* b0a    = (const float*)d_in[16];
    const float* w0b    = (const float*)d_in[17];
    const float* b0b    = (const float*)d_in[18];
    const float* w1a    = (const float*)d_in[19];
    const float* b1a    = (const float*)d_in[20];
    const float* w1b    = (const float*)d_in[21];
    const float* b1b    = (const float*)d_in[22];
    float* out = (float*)d_out;

    float* hA     = (float*)d_ws;          // [BN, D]
    float* hB     = hA + BND;
    float* Mu     = hB + BND;              // conv1 messages; aliased as `part`
    float* M2     = Mu + BND;              // conv2 messages
    float* hidden = M2 + BND;              // [2][8][H] = 2048 floats
    int* cnt      = (int*)(hidden + 2048); // [N]
    int* cursor   = cnt + N;               // [N]
    int* offs     = cursor + N;            // [N+1]
    int* elist    = offs + N + 1;          // [E]
    float* part   = Mu;                    // [2][XB][1024] = 2.048M floats <= BND

    hipMemsetAsync(hidden, 0, (2048 + 2 * N) * sizeof(float), stream);

    k_count<<<(E + 255) / 256, 256, 0, stream>>>(edges, cnt);
    k_scan<<<1, 256, 0, stream>>>(cnt, offs);
    k_fill<<<(E + 255) / 256, 256, 0, stream>>>(edges, offs, cursor, elist);

    // conv1 prepare (also materializes hA = x*emb)
    k_prepare<<<(BN + 127) / 128, 512, 0, stream>>>(x, emb, nullptr, c1_pw1, c1_pw2, Mu, hA);
    // conv1 gather+update, fused with conv2 prepare (writes hB and M2)
    k_conv<1><<<BN / 64, 512, 0, stream>>>(hA, Mu, offs, elist,
                                           c1_uw1, c1_ub1, c1_uw2, c1_ub2, hB,
                                           c2_pw1, c2_pw2, M2);
    // conv2 gather+update (writes hA = phi)
    k_conv<0><<<BN / 64, 512, 0, stream>>>(hB, M2, offs, elist,
                                           c2_uw1, c2_ub1, c2_uw2, c2_ub2, hA,
                                           nullptr, nullptr, nullptr);

    // heads: partials (Mu is dead scratch by now) -> reduce -> final
    k_head<<<dim3(XB, 2), 256, 0, stream>>>(hA, w0a, w1a, part);
    k_reduce<<<dim3(8, 16), 256, 0, stream>>>(part, hidden);
    k_final<<<1, 64, 0, stream>>>(hidden, b0a, w0b, b0b, b1a, w1b, b1b, out);
}